// Round 3
// baseline (718.458 us; speedup 1.0000x reference)
//
#include <hip/hip_runtime.h>
#include <stdint.h>

#define N_TOK 6144
#define DMODEL 768
#define NHEAD 3
#define DHEAD 256
#define NWORDS (N_TOK/32)  // 192 mask words per row
#define NT NWORDS          // 192 key tiles of 32 keys

typedef __bf16 bf16x8 __attribute__((ext_vector_type(8)));
typedef float f32x4 __attribute__((ext_vector_type(4)));
typedef unsigned short u16;
typedef u16 u16x8 __attribute__((ext_vector_type(8)));
typedef u16 u16x4 __attribute__((ext_vector_type(4)));
typedef unsigned int u32;

__device__ __forceinline__ u16 f2bf(float f) {
  union { float f; u32 u; } v; v.f = f;
  u32 u = v.u;
  u32 r = (u + 0x7FFFu + ((u >> 16) & 1u)) >> 16;  // RNE
  return (u16)r;
}
__device__ __forceinline__ float lrelu(float v) { return v >= 0.f ? v : 0.2f * v; }

// ---------------- adj [N][N] int32 -> bitmask [N][NWORDS] ----------------
__global__ __launch_bounds__(256) void pack_adj(const int* __restrict__ adj,
                                                u32* __restrict__ bits) {
  size_t wid = (size_t)blockIdx.x * 256 + threadIdx.x;   // one 32-key word
  const int4* p = reinterpret_cast<const int4*>(adj + wid * 32);
  u32 m = 0;
#pragma unroll
  for (int i = 0; i < 8; ++i) {
    int4 v = p[i];
    m |= (v.x != 0 ? 1u : 0u) << (i * 4 + 0);
    m |= (v.y != 0 ? 1u : 0u) << (i * 4 + 1);
    m |= (v.z != 0 ? 1u : 0u) << (i * 4 + 2);
    m |= (v.w != 0 ? 1u : 0u) << (i * 4 + 3);
  }
  bits[wid] = m;
}

// ---------------- bf16 transpose: src[N][768] -> dst[768][N] ----------------
__global__ __launch_bounds__(256) void transpose_bf(const u16* __restrict__ src,
                                                    u16* __restrict__ dst) {
  __shared__ u16 t[64][72];
  const int n0 = blockIdx.x * 64, d0 = blockIdx.y * 64;
  const int tid = threadIdx.x;
#pragma unroll
  for (int i = 0; i < 2; ++i) {
    int c = tid + i * 256;
    int r = c >> 3, c8 = (c & 7) * 8;
    *reinterpret_cast<u16x8*>(&t[r][c8]) =
        *reinterpret_cast<const u16x8*>(src + (size_t)(n0 + r) * DMODEL + d0 + c8);
  }
  __syncthreads();
#pragma unroll
  for (int i = 0; i < 2; ++i) {
    int c = tid + i * 256;
    int dr = c >> 3, n8 = (c & 7) * 8;
    u16x8 v;
#pragma unroll
    for (int j = 0; j < 8; ++j) v[j] = t[n8 + j][dr];
    *reinterpret_cast<u16x8*>(dst + (size_t)(d0 + dr) * N_TOK + n0 + n8) = v;
  }
}

// ---------------- NT GEMM: C[6144,768] = A[6144,768] @ W[768,768]^T ----------------
template <int ABF, int FINAL>
__global__ __launch_bounds__(256) void gemm_nt(const void* __restrict__ Aptr,
                                               const float* __restrict__ W,
                                               const float* __restrict__ bias,
                                               const float* __restrict__ resid,
                                               u16* __restrict__ out_bf,
                                               float* __restrict__ out_f) {
  __shared__ u16 As[128][72];
  __shared__ u16 Bs[128][72];
  const int tid = threadIdx.x;
  const int w = tid >> 6, lane = tid & 63, lr = lane & 15, lg = lane >> 4;
  const int m0 = blockIdx.x * 128, n0 = blockIdx.y * 128;
  const int wr = (w >> 1) * 64, wc = (w & 1) * 64;
  f32x4 acc[4][4] = {};
  for (int kt = 0; kt < DMODEL / 64; ++kt) {
    __syncthreads();
#pragma unroll
    for (int i = 0; i < 4; ++i) {
      int c = tid + i * 256;
      int row = c >> 3, c8 = (c & 7) * 8;
      int gcol = kt * 64 + c8;
      if (ABF) {
        *reinterpret_cast<u16x8*>(&As[row][c8]) = *reinterpret_cast<const u16x8*>(
            (const u16*)Aptr + (size_t)(m0 + row) * DMODEL + gcol);
      } else {
        const float* src = (const float*)Aptr + (size_t)(m0 + row) * DMODEL + gcol;
        float4 f0 = *reinterpret_cast<const float4*>(src);
        float4 f1 = *reinterpret_cast<const float4*>(src + 4);
        u16x8 v = {f2bf(f0.x), f2bf(f0.y), f2bf(f0.z), f2bf(f0.w),
                   f2bf(f1.x), f2bf(f1.y), f2bf(f1.z), f2bf(f1.w)};
        *reinterpret_cast<u16x8*>(&As[row][c8]) = v;
      }
      const float* wsrc = W + (size_t)(n0 + row) * DMODEL + gcol;
      float4 g0 = *reinterpret_cast<const float4*>(wsrc);
      float4 g1 = *reinterpret_cast<const float4*>(wsrc + 4);
      u16x8 wv = {f2bf(g0.x), f2bf(g0.y), f2bf(g0.z), f2bf(g0.w),
                  f2bf(g1.x), f2bf(g1.y), f2bf(g1.z), f2bf(g1.w)};
      *reinterpret_cast<u16x8*>(&Bs[row][c8]) = wv;
    }
    __syncthreads();
#pragma unroll
    for (int ks = 0; ks < 2; ++ks) {
      bf16x8 a[4], b[4];
#pragma unroll
      for (int mi = 0; mi < 4; ++mi)
        a[mi] = *reinterpret_cast<const bf16x8*>(&As[wr + mi * 16 + lr][ks * 32 + lg * 8]);
#pragma unroll
      for (int ni = 0; ni < 4; ++ni)
        b[ni] = *reinterpret_cast<const bf16x8*>(&Bs[wc + ni * 16 + lr][ks * 32 + lg * 8]);
#pragma unroll
      for (int mi = 0; mi < 4; ++mi)
#pragma unroll
        for (int ni = 0; ni < 4; ++ni)
          acc[mi][ni] =
              __builtin_amdgcn_mfma_f32_16x16x32_bf16(a[mi], b[ni], acc[mi][ni], 0, 0, 0);
    }
  }
#pragma unroll
  for (int mi = 0; mi < 4; ++mi)
#pragma unroll
    for (int ni = 0; ni < 4; ++ni)
#pragma unroll
      for (int r = 0; r < 4; ++r) {
        int grow = m0 + wr + mi * 16 + lg * 4 + r;
        int gcol = n0 + wc + ni * 16 + lr;
        float v = lrelu(acc[mi][ni][r] + bias[gcol]);
        size_t idx = (size_t)grow * DMODEL + gcol;
        if (FINAL)
          out_f[idx] = resid[idx] + v;
        else
          out_bf[idx] = f2bf(v);
      }
}

// ---------------- fused masked flash attention ----------------
// 256 thr = 4 waves, each wave owns 16 q-rows of one head. 32 keys per iter.
// blockIdx.z = key-split index; each split handles NT/SPLIT tiles and writes
// f32 partials (O, m, l) that attn_combine folds together.
template <int SPLIT>
__global__ __launch_bounds__(256, 4) void attn_fused(
    const u16* __restrict__ Kmat,  // x_new bf16 [N][768]
    const u16* __restrict__ Qmat,  // q bf16 [N][768]
    const u16* __restrict__ VT,    // x_new^T bf16 [768][N]
    const u32* __restrict__ bits,  // [N][NWORDS]
    const float* __restrict__ x,   // residual [N][768] f32 (SPLIT==1 only)
    u16* __restrict__ out2,        // bf16 [N][768] (SPLIT==1 only)
    float* __restrict__ Opart,     // [SPLIT][N][768] f32 partial O
    float* __restrict__ mlpart) {  // [SPLIT][H][N][2] f32 (m, l)
  __shared__ u16 Ks[32][264];   // [key][dh]   stride 528B: read banks at uniform floor
  __shared__ u16 Vs[256][36];   // [dh][key]   stride 72B: 18r mod 32 covers all residues
  __shared__ u16 Ps[4][16][36]; // per-wave [q][key]
  __shared__ u32 adjw[64];
  const int tid = threadIdx.x;
  const int w = tid >> 6, lane = tid & 63, lr = lane & 15, lg = lane >> 4;
  const int q0 = blockIdx.x * 64;
  const int h = blockIdx.y;
  const int z = blockIdx.z;
  const int qrow = q0 + w * 16 + lr;

  // Q fragments in registers: lane holds q-row, dh = s*32 + lg*8 .. +7
  bf16x8 qf[8];
  {
    const u16* qrowp = Qmat + (size_t)qrow * DMODEL + h * DHEAD + lg * 8;
#pragma unroll
    for (int s = 0; s < 8; ++s) qf[s] = *reinterpret_cast<const bf16x8*>(qrowp + s * 32);
  }
  f32x4 o[16] = {};
  float m = -1e30f, lsum = 0.f;

  const int t0 = z * (NT / SPLIT), t1 = t0 + NT / SPLIT;
  for (int kt = t0; kt < t1; ++kt) {
    __syncthreads();
#pragma unroll
    for (int i = 0; i < 4; ++i) {
      int c = tid + i * 256;
      {  // K tile 32x256
        int kr = c >> 5, c8 = (c & 31) * 8;
        *reinterpret_cast<u16x8*>(&Ks[kr][c8]) = *reinterpret_cast<const u16x8*>(
            Kmat + (size_t)(kt * 32 + kr) * DMODEL + h * DHEAD + c8);
      }
      {  // V^T tile 256x32
        int dr = c >> 2, c8 = (c & 3) * 8;
        *reinterpret_cast<u16x8*>(&Vs[dr][c8]) = *reinterpret_cast<const u16x8*>(
            VT + (size_t)(h * DHEAD + dr) * N_TOK + kt * 32 + c8);
      }
    }
    if (tid < 64) adjw[tid] = bits[(size_t)(q0 + tid) * NWORDS + kt];
    __syncthreads();

    // S^T[key, q] = K_tile @ Q^T  (swapped -> lane owns q = lr)
    f32x4 st[2] = {};
#pragma unroll
    for (int s = 0; s < 8; ++s) {
      bf16x8 k0 = *reinterpret_cast<const bf16x8*>(&Ks[lr][s * 32 + lg * 8]);
      bf16x8 k1 = *reinterpret_cast<const bf16x8*>(&Ks[16 + lr][s * 32 + lg * 8]);
      st[0] = __builtin_amdgcn_mfma_f32_16x16x32_bf16(k0, qf[s], st[0], 0, 0, 0);
      st[1] = __builtin_amdgcn_mfma_f32_16x16x32_bf16(k1, qf[s], st[1], 0, 0, 0);
    }
    const u32 word = adjw[w * 16 + lr];
    float pv[2][4];
    float tmax = -1e30f;
#pragma unroll
    for (int kb = 0; kb < 2; ++kb)
#pragma unroll
      for (int r = 0; r < 4; ++r) {
        int keyl = kb * 16 + lg * 4 + r;
        float sv = ((word >> keyl) & 1u) ? st[kb][r] * 0.1f : -1e30f;
        pv[kb][r] = sv;
        tmax = fmaxf(tmax, sv);
      }
    tmax = fmaxf(tmax, __shfl_xor(tmax, 16));
    tmax = fmaxf(tmax, __shfl_xor(tmax, 32));
    const bool grew = __any(tmax > m);  // exact: if !grew, every row's alpha == 1
    float mnew = fmaxf(m, tmax);
    float alpha = __expf(m - mnew);
    float rsum = 0.f;
#pragma unroll
    for (int kb = 0; kb < 2; ++kb) {
      u16x4 pk;
#pragma unroll
      for (int r = 0; r < 4; ++r) {
        float p = __expf(pv[kb][r] - mnew);
        rsum += p;
        pk[r] = f2bf(p);
      }
      *reinterpret_cast<u16x4*>(&Ps[w][lr][kb * 16 + lg * 4]) = pk;
    }
    rsum += __shfl_xor(rsum, 16);
    rsum += __shfl_xor(rsum, 32);
    lsum = lsum * alpha + rsum;
    m = mnew;
    if (grew) {
      float ar[4];
#pragma unroll
      for (int r = 0; r < 4; ++r) ar[r] = __shfl(alpha, lg * 4 + r);
#pragma unroll
      for (int d = 0; d < 16; ++d) {
        o[d][0] *= ar[0]; o[d][1] *= ar[1]; o[d][2] *= ar[2]; o[d][3] *= ar[3];
      }
    }
    // Ps written/read within the same wave: only need LDS op completion
    asm volatile("s_waitcnt lgkmcnt(0)" ::: "memory");
    __builtin_amdgcn_sched_barrier(0);  // keep MFMA below the wait (rule #18)
    bf16x8 pf = *reinterpret_cast<const bf16x8*>(&Ps[w][lr][lg * 8]);
#pragma unroll
    for (int d = 0; d < 16; ++d) {
      bf16x8 vf = *reinterpret_cast<const bf16x8*>(&Vs[d * 16 + lr][lg * 8]);
      o[d] = __builtin_amdgcn_mfma_f32_16x16x32_bf16(pf, vf, o[d], 0, 0, 0);
    }
  }

  if (SPLIT == 1) {
    float ls[4];
#pragma unroll
    for (int r = 0; r < 4; ++r) ls[r] = __shfl(lsum, lg * 4 + r);
#pragma unroll
    for (int d = 0; d < 16; ++d)
#pragma unroll
      for (int r = 0; r < 4; ++r) {
        int grow = q0 + w * 16 + lg * 4 + r;
        int gcol = h * DHEAD + d * 16 + lr;
        size_t idx = (size_t)grow * DMODEL + gcol;
        out2[idx] = f2bf(x[idx] + o[d][r] / ls[r]);
      }
  } else {
    float* Op = Opart + (size_t)z * N_TOK * DMODEL;
#pragma unroll
    for (int d = 0; d < 16; ++d)
#pragma unroll
      for (int r = 0; r < 4; ++r) {
        int grow = q0 + w * 16 + lg * 4 + r;
        int gcol = h * DHEAD + d * 16 + lr;
        Op[(size_t)grow * DMODEL + gcol] = o[d][r];
      }
    if (lane < 16) {
      float2 v = make_float2(m, lsum);
      *reinterpret_cast<float2*>(mlpart + ((size_t)(z * NHEAD + h) * N_TOK + qrow) * 2) = v;
    }
  }
}

// ---------------- combine SPLIT key-split partials: out2 = bf16(x + O/L) ----------------
template <int SPLIT>
__global__ __launch_bounds__(256) void attn_combine(const float* __restrict__ Opart,
                                                    const float* __restrict__ mlpart,
                                                    const float* __restrict__ x,
                                                    u16* __restrict__ out2) {
  int g = blockIdx.x * 256 + threadIdx.x;  // one float4 group
  int q = g / (DMODEL / 4);
  int col = (g % (DMODEL / 4)) * 4;
  int h = col >> 8;
  float2 ml[SPLIT];
  float M = -1e30f;
#pragma unroll
  for (int s = 0; s < SPLIT; ++s) {
    ml[s] = *reinterpret_cast<const float2*>(
        mlpart + ((size_t)(s * NHEAD + h) * N_TOK + q) * 2);
    M = fmaxf(M, ml[s].x);
  }
  float L = 0.f;
  float e[SPLIT];
#pragma unroll
  for (int s = 0; s < SPLIT; ++s) {
    e[s] = __expf(ml[s].x - M);
    L += ml[s].y * e[s];
  }
  float rL = 1.f / L;
  size_t idx = (size_t)q * DMODEL + col;
  float4 acc = make_float4(0.f, 0.f, 0.f, 0.f);
#pragma unroll
  for (int s = 0; s < SPLIT; ++s) {
    float4 O = *reinterpret_cast<const float4*>(Opart + (size_t)s * N_TOK * DMODEL + idx);
    acc.x += O.x * e[s]; acc.y += O.y * e[s]; acc.z += O.z * e[s]; acc.w += O.w * e[s];
  }
  float4 xv = *reinterpret_cast<const float4*>(x + idx);
  u16x4 r;
  r[0] = f2bf(xv.x + acc.x * rL);
  r[1] = f2bf(xv.y + acc.y * rL);
  r[2] = f2bf(xv.z + acc.z * rL);
  r[3] = f2bf(xv.w + acc.w * rL);
  *reinterpret_cast<u16x4*>(out2 + idx) = r;
}

extern "C" void kernel_launch(void* const* d_in, const int* in_sizes, int n_in,
                              void* d_out, int out_size, void* d_ws, size_t ws_size,
                              hipStream_t stream) {
  const float* x     = (const float*)d_in[0];
  const int*   adj   = (const int*)d_in[1];
  const float* W_fc  = (const float*)d_in[2];
  const float* b_fc  = (const float*)d_in[3];
  const float* W_qfc = (const float*)d_in[4];
  const float* b_qfc = (const float*)d_in[5];
  const float* W_fin = (const float*)d_in[6];
  const float* b_fin = (const float*)d_in[7];
  float* out = (float*)d_out;

  char* ws = (char*)d_ws;
  size_t off = 0;
  auto alloc = [&](size_t bytes) {
    char* p = ws + off;
    off += (bytes + 255) & ~(size_t)255;
    return p;
  };
  u16* xnew_bf = (u16*)alloc((size_t)N_TOK * DMODEL * 2);
  u16* q_bf    = (u16*)alloc((size_t)N_TOK * DMODEL * 2);
  u16* xT      = (u16*)alloc((size_t)DMODEL * N_TOK * 2);
  u16* out2_bf = (u16*)alloc((size_t)N_TOK * DMODEL * 2);
  u32* bits    = (u32*)alloc((size_t)N_TOK * NWORDS * 4);
  size_t base_off = off;
  float* Opart  = (float*)alloc((size_t)4 * N_TOK * DMODEL * 4);
  float* mlpart = (float*)alloc((size_t)4 * NHEAD * N_TOK * 2 * 4);
  size_t need4 = off;
  size_t need2 = base_off + ((size_t)2 * N_TOK * DMODEL * 4 + 256) +
                 ((size_t)2 * NHEAD * N_TOK * 2 * 4 + 256);
  const int split = (ws_size >= need4) ? 4 : (ws_size >= need2) ? 2 : 1;

  pack_adj<<<N_TOK * NWORDS / 256, 256, 0, stream>>>(adj, bits);
  dim3 ggrid(N_TOK / 128, DMODEL / 128);
  gemm_nt<0, 0><<<ggrid, 256, 0, stream>>>(x, W_fc, b_fc, nullptr, xnew_bf, nullptr);
  gemm_nt<1, 0><<<ggrid, 256, 0, stream>>>(xnew_bf, W_qfc, b_qfc, nullptr, q_bf, nullptr);
  transpose_bf<<<dim3(N_TOK / 64, DMODEL / 64), 256, 0, stream>>>(xnew_bf, xT);
  if (split == 4) {
    attn_fused<4><<<dim3(N_TOK / 64, NHEAD, 4), 256, 0, stream>>>(
        xnew_bf, q_bf, xT, bits, x, out2_bf, Opart, mlpart);
    attn_combine<4><<<N_TOK * DMODEL / 4 / 256, 256, 0, stream>>>(Opart, mlpart, x, out2_bf);
  } else if (split == 2) {
    attn_fused<2><<<dim3(N_TOK / 64, NHEAD, 2), 256, 0, stream>>>(
        xnew_bf, q_bf, xT, bits, x, out2_bf, Opart, mlpart);
    attn_combine<2><<<N_TOK * DMODEL / 4 / 256, 256, 0, stream>>>(Opart, mlpart, x, out2_bf);
  } else {
    attn_fused<1><<<dim3(N_TOK / 64, NHEAD, 1), 256, 0, stream>>>(
        xnew_bf, q_bf, xT, bits, x, out2_bf, Opart, mlpart);
  }
  gemm_nt<1, 1><<<ggrid, 256, 0, stream>>>(out2_bf, W_fin, b_fin, x, nullptr, out);
}

// Round 4
// 598.490 us; speedup vs baseline: 1.2005x; 1.2005x over previous
//
#include <hip/hip_runtime.h>
#include <stdint.h>

#define N_TOK 6144
#define DMODEL 768
#define NHEAD 3
#define DHEAD 256
#define NWORDS (N_TOK/32)  // 192 mask words per row
#define NT NWORDS          // 192 key tiles of 32 keys

typedef __bf16 bf16x8 __attribute__((ext_vector_type(8)));
typedef float f32x4 __attribute__((ext_vector_type(4)));
typedef unsigned short u16;
typedef u16 u16x8 __attribute__((ext_vector_type(8)));
typedef u16 u16x4 __attribute__((ext_vector_type(4)));
typedef unsigned int u32;

__device__ __forceinline__ u16 f2bf(float f) {
  union { float f; u32 u; } v; v.f = f;
  u32 u = v.u;
  u32 r = (u + 0x7FFFu + ((u >> 16) & 1u)) >> 16;  // RNE
  return (u16)r;
}
__device__ __forceinline__ float lrelu(float v) { return v >= 0.f ? v : 0.2f * v; }

// ---------------- adj [N][N] int32 -> bitmask [N][NWORDS] ----------------
__global__ __launch_bounds__(256) void pack_adj(const int* __restrict__ adj,
                                                u32* __restrict__ bits) {
  size_t wid = (size_t)blockIdx.x * 256 + threadIdx.x;   // one 32-key word
  const int4* p = reinterpret_cast<const int4*>(adj + wid * 32);
  u32 m = 0;
#pragma unroll
  for (int i = 0; i < 8; ++i) {
    int4 v = p[i];
    m |= (v.x != 0 ? 1u : 0u) << (i * 4 + 0);
    m |= (v.y != 0 ? 1u : 0u) << (i * 4 + 1);
    m |= (v.z != 0 ? 1u : 0u) << (i * 4 + 2);
    m |= (v.w != 0 ? 1u : 0u) << (i * 4 + 3);
  }
  bits[wid] = m;
}

// ---------------- bf16 transpose: src[N][768] -> dst[768][N] ----------------
__global__ __launch_bounds__(256) void transpose_bf(const u16* __restrict__ src,
                                                    u16* __restrict__ dst) {
  __shared__ u16 t[64][72];
  const int n0 = blockIdx.x * 64, d0 = blockIdx.y * 64;
  const int tid = threadIdx.x;
#pragma unroll
  for (int i = 0; i < 2; ++i) {
    int c = tid + i * 256;
    int r = c >> 3, c8 = (c & 7) * 8;
    *reinterpret_cast<u16x8*>(&t[r][c8]) =
        *reinterpret_cast<const u16x8*>(src + (size_t)(n0 + r) * DMODEL + d0 + c8);
  }
  __syncthreads();
#pragma unroll
  for (int i = 0; i < 2; ++i) {
    int c = tid + i * 256;
    int dr = c >> 3, n8 = (c & 7) * 8;
    u16x8 v;
#pragma unroll
    for (int j = 0; j < 8; ++j) v[j] = t[n8 + j][dr];
    *reinterpret_cast<u16x8*>(dst + (size_t)(d0 + dr) * N_TOK + n0 + n8) = v;
  }
}

// ---------------- NT GEMM: C[6144,768] = A[6144,768] @ W[768,768]^T ----------------
template <int ABF, int FINAL>
__global__ __launch_bounds__(256) void gemm_nt(const void* __restrict__ Aptr,
                                               const float* __restrict__ W,
                                               const float* __restrict__ bias,
                                               const float* __restrict__ resid,
                                               u16* __restrict__ out_bf,
                                               float* __restrict__ out_f) {
  __shared__ u16 As[128][72];
  __shared__ u16 Bs[128][72];
  const int tid = threadIdx.x;
  const int w = tid >> 6, lane = tid & 63, lr = lane & 15, lg = lane >> 4;
  const int m0 = blockIdx.x * 128, n0 = blockIdx.y * 128;
  const int wr = (w >> 1) * 64, wc = (w & 1) * 64;
  f32x4 acc[4][4] = {};
  for (int kt = 0; kt < DMODEL / 64; ++kt) {
    __syncthreads();
#pragma unroll
    for (int i = 0; i < 4; ++i) {
      int c = tid + i * 256;
      int row = c >> 3, c8 = (c & 7) * 8;
      int gcol = kt * 64 + c8;
      if (ABF) {
        *reinterpret_cast<u16x8*>(&As[row][c8]) = *reinterpret_cast<const u16x8*>(
            (const u16*)Aptr + (size_t)(m0 + row) * DMODEL + gcol);
      } else {
        const float* src = (const float*)Aptr + (size_t)(m0 + row) * DMODEL + gcol;
        float4 f0 = *reinterpret_cast<const float4*>(src);
        float4 f1 = *reinterpret_cast<const float4*>(src + 4);
        u16x8 v = {f2bf(f0.x), f2bf(f0.y), f2bf(f0.z), f2bf(f0.w),
                   f2bf(f1.x), f2bf(f1.y), f2bf(f1.z), f2bf(f1.w)};
        *reinterpret_cast<u16x8*>(&As[row][c8]) = v;
      }
      const float* wsrc = W + (size_t)(n0 + row) * DMODEL + gcol;
      float4 g0 = *reinterpret_cast<const float4*>(wsrc);
      float4 g1 = *reinterpret_cast<const float4*>(wsrc + 4);
      u16x8 wv = {f2bf(g0.x), f2bf(g0.y), f2bf(g0.z), f2bf(g0.w),
                  f2bf(g1.x), f2bf(g1.y), f2bf(g1.z), f2bf(g1.w)};
      *reinterpret_cast<u16x8*>(&Bs[row][c8]) = wv;
    }
    __syncthreads();
#pragma unroll
    for (int ks = 0; ks < 2; ++ks) {
      bf16x8 a[4], b[4];
#pragma unroll
      for (int mi = 0; mi < 4; ++mi)
        a[mi] = *reinterpret_cast<const bf16x8*>(&As[wr + mi * 16 + lr][ks * 32 + lg * 8]);
#pragma unroll
      for (int ni = 0; ni < 4; ++ni)
        b[ni] = *reinterpret_cast<const bf16x8*>(&Bs[wc + ni * 16 + lr][ks * 32 + lg * 8]);
#pragma unroll
      for (int mi = 0; mi < 4; ++mi)
#pragma unroll
        for (int ni = 0; ni < 4; ++ni)
          acc[mi][ni] =
              __builtin_amdgcn_mfma_f32_16x16x32_bf16(a[mi], b[ni], acc[mi][ni], 0, 0, 0);
    }
  }
#pragma unroll
  for (int mi = 0; mi < 4; ++mi)
#pragma unroll
    for (int ni = 0; ni < 4; ++ni)
#pragma unroll
      for (int r = 0; r < 4; ++r) {
        int grow = m0 + wr + mi * 16 + lg * 4 + r;
        int gcol = n0 + wc + ni * 16 + lr;
        float v = lrelu(acc[mi][ni][r] + bias[gcol]);
        size_t idx = (size_t)grow * DMODEL + gcol;
        if (FINAL)
          out_f[idx] = resid[idx] + v;
        else
          out_bf[idx] = f2bf(v);
      }
}

// ---------------- fused masked flash attention ----------------
// 256 thr = 4 waves, each wave owns 16 q-rows of one head. 32 keys per iter.
// blockIdx.z = key-split index; each split handles NT/SPLIT tiles and writes
// f32 partials (O, m, l) that attn_combine folds together.
// NOTE: no min-waves hint here — round 3 showed __launch_bounds__(256,4)
// caps arch-VGPRs at 64 and spills o[16]/qf[8] to scratch (808 MB/dispatch).
template <int SPLIT>
__global__ __launch_bounds__(256) void attn_fused(
    const u16* __restrict__ Kmat,  // x_new bf16 [N][768]
    const u16* __restrict__ Qmat,  // q bf16 [N][768]
    const u16* __restrict__ VT,    // x_new^T bf16 [768][N]
    const u32* __restrict__ bits,  // [N][NWORDS]
    const float* __restrict__ x,   // residual [N][768] f32 (SPLIT==1 only)
    u16* __restrict__ out2,        // bf16 [N][768] (SPLIT==1 only)
    float* __restrict__ Opart,     // [SPLIT][N][768] f32 partial O
    float* __restrict__ mlpart) {  // [SPLIT][H][N][2] f32 (m, l)
  __shared__ u16 Ks[32][264];   // [key][dh]
  __shared__ u16 Vs[256][36];   // [dh][key]
  __shared__ u16 Ps[4][16][36]; // per-wave [q][key]
  __shared__ u32 adjw[64];
  const int tid = threadIdx.x;
  const int w = tid >> 6, lane = tid & 63, lr = lane & 15, lg = lane >> 4;
  const int q0 = blockIdx.x * 64;
  const int h = blockIdx.y;
  const int z = blockIdx.z;
  const int qrow = q0 + w * 16 + lr;

  // Q fragments in registers: lane holds q-row, dh = s*32 + lg*8 .. +7
  bf16x8 qf[8];
  {
    const u16* qrowp = Qmat + (size_t)qrow * DMODEL + h * DHEAD + lg * 8;
#pragma unroll
    for (int s = 0; s < 8; ++s) qf[s] = *reinterpret_cast<const bf16x8*>(qrowp + s * 32);
  }
  f32x4 o[16] = {};
  float m = -1e30f, lsum = 0.f;

  const int t0 = z * (NT / SPLIT), t1 = t0 + NT / SPLIT;
  for (int kt = t0; kt < t1; ++kt) {
    __syncthreads();
#pragma unroll
    for (int i = 0; i < 4; ++i) {
      int c = tid + i * 256;
      {  // K tile 32x256
        int kr = c >> 5, c8 = (c & 31) * 8;
        *reinterpret_cast<u16x8*>(&Ks[kr][c8]) = *reinterpret_cast<const u16x8*>(
            Kmat + (size_t)(kt * 32 + kr) * DMODEL + h * DHEAD + c8);
      }
      {  // V^T tile 256x32
        int dr = c >> 2, c8 = (c & 3) * 8;
        *reinterpret_cast<u16x8*>(&Vs[dr][c8]) = *reinterpret_cast<const u16x8*>(
            VT + (size_t)(h * DHEAD + dr) * N_TOK + kt * 32 + c8);
      }
    }
    if (tid < 64) adjw[tid] = bits[(size_t)(q0 + tid) * NWORDS + kt];
    __syncthreads();

    // S^T[key, q] = K_tile @ Q^T  (swapped -> lane owns q = lr)
    f32x4 st[2] = {};
#pragma unroll
    for (int s = 0; s < 8; ++s) {
      bf16x8 k0 = *reinterpret_cast<const bf16x8*>(&Ks[lr][s * 32 + lg * 8]);
      bf16x8 k1 = *reinterpret_cast<const bf16x8*>(&Ks[16 + lr][s * 32 + lg * 8]);
      st[0] = __builtin_amdgcn_mfma_f32_16x16x32_bf16(k0, qf[s], st[0], 0, 0, 0);
      st[1] = __builtin_amdgcn_mfma_f32_16x16x32_bf16(k1, qf[s], st[1], 0, 0, 0);
    }
    const u32 word = adjw[w * 16 + lr];
    float pv[2][4];
    float tmax = -1e30f;
#pragma unroll
    for (int kb = 0; kb < 2; ++kb)
#pragma unroll
      for (int r = 0; r < 4; ++r) {
        int keyl = kb * 16 + lg * 4 + r;
        float sv = ((word >> keyl) & 1u) ? st[kb][r] * 0.1f : -1e30f;
        pv[kb][r] = sv;
        tmax = fmaxf(tmax, sv);
      }
    tmax = fmaxf(tmax, __shfl_xor(tmax, 16));
    tmax = fmaxf(tmax, __shfl_xor(tmax, 32));
    const bool grew = __any(tmax > m);  // exact: if !grew, every row's alpha == 1
    float mnew = fmaxf(m, tmax);
    float alpha = __expf(m - mnew);
    float rsum = 0.f;
#pragma unroll
    for (int kb = 0; kb < 2; ++kb) {
      u16x4 pk;
#pragma unroll
      for (int r = 0; r < 4; ++r) {
        float p = __expf(pv[kb][r] - mnew);
        rsum += p;
        pk[r] = f2bf(p);
      }
      *reinterpret_cast<u16x4*>(&Ps[w][lr][kb * 16 + lg * 4]) = pk;
    }
    rsum += __shfl_xor(rsum, 16);
    rsum += __shfl_xor(rsum, 32);
    lsum = lsum * alpha + rsum;
    m = mnew;
    if (grew) {
      float ar[4];
#pragma unroll
      for (int r = 0; r < 4; ++r) ar[r] = __shfl(alpha, lg * 4 + r);
#pragma unroll
      for (int d = 0; d < 16; ++d) {
        o[d][0] *= ar[0]; o[d][1] *= ar[1]; o[d][2] *= ar[2]; o[d][3] *= ar[3];
      }
    }
    // Ps written/read within the same wave: only need LDS op completion
    asm volatile("s_waitcnt lgkmcnt(0)" ::: "memory");
    __builtin_amdgcn_sched_barrier(0);  // keep MFMA below the wait (rule #18)
    bf16x8 pf = *reinterpret_cast<const bf16x8*>(&Ps[w][lr][lg * 8]);
#pragma unroll
    for (int d = 0; d < 16; ++d) {
      bf16x8 vf = *reinterpret_cast<const bf16x8*>(&Vs[d * 16 + lr][lg * 8]);
      o[d] = __builtin_amdgcn_mfma_f32_16x16x32_bf16(pf, vf, o[d], 0, 0, 0);
    }
  }

  if (SPLIT == 1) {
    float ls[4];
#pragma unroll
    for (int r = 0; r < 4; ++r) ls[r] = __shfl(lsum, lg * 4 + r);
#pragma unroll
    for (int d = 0; d < 16; ++d)
#pragma unroll
      for (int r = 0; r < 4; ++r) {
        int grow = q0 + w * 16 + lg * 4 + r;
        int gcol = h * DHEAD + d * 16 + lr;
        size_t idx = (size_t)grow * DMODEL + gcol;
        out2[idx] = f2bf(x[idx] + o[d][r] / ls[r]);
      }
  } else {
    float* Op = Opart + (size_t)z * N_TOK * DMODEL;
#pragma unroll
    for (int d = 0; d < 16; ++d)
#pragma unroll
      for (int r = 0; r < 4; ++r) {
        int grow = q0 + w * 16 + lg * 4 + r;
        int gcol = h * DHEAD + d * 16 + lr;
        Op[(size_t)grow * DMODEL + gcol] = o[d][r];
      }
    if (lane < 16) {
      float2 v = make_float2(m, lsum);
      *reinterpret_cast<float2*>(mlpart + ((size_t)(z * NHEAD + h) * N_TOK + qrow) * 2) = v;
    }
  }
}

// ---------------- combine SPLIT key-split partials: out2 = bf16(x + O/L) ----------------
template <int SPLIT>
__global__ __launch_bounds__(256) void attn_combine(const float* __restrict__ Opart,
                                                    const float* __restrict__ mlpart,
                                                    const float* __restrict__ x,
                                                    u16* __restrict__ out2) {
  int g = blockIdx.x * 256 + threadIdx.x;  // one float4 group
  int q = g / (DMODEL / 4);
  int col = (g % (DMODEL / 4)) * 4;
  int h = col >> 8;
  float2 ml[SPLIT];
  float M = -1e30f;
#pragma unroll
  for (int s = 0; s < SPLIT; ++s) {
    ml[s] = *reinterpret_cast<const float2*>(
        mlpart + ((size_t)(s * NHEAD + h) * N_TOK + q) * 2);
    M = fmaxf(M, ml[s].x);
  }
  float L = 0.f;
  float e[SPLIT];
#pragma unroll
  for (int s = 0; s < SPLIT; ++s) {
    e[s] = __expf(ml[s].x - M);
    L += ml[s].y * e[s];
  }
  float rL = 1.f / L;
  size_t idx = (size_t)q * DMODEL + col;
  float4 acc = make_float4(0.f, 0.f, 0.f, 0.f);
#pragma unroll
  for (int s = 0; s < SPLIT; ++s) {
    float4 O = *reinterpret_cast<const float4*>(Opart + (size_t)s * N_TOK * DMODEL + idx);
    acc.x += O.x * e[s]; acc.y += O.y * e[s]; acc.z += O.z * e[s]; acc.w += O.w * e[s];
  }
  float4 xv = *reinterpret_cast<const float4*>(x + idx);
  u16x4 r;
  r[0] = f2bf(xv.x + acc.x * rL);
  r[1] = f2bf(xv.y + acc.y * rL);
  r[2] = f2bf(xv.z + acc.z * rL);
  r[3] = f2bf(xv.w + acc.w * rL);
  *reinterpret_cast<u16x4*>(out2 + idx) = r;
}

extern "C" void kernel_launch(void* const* d_in, const int* in_sizes, int n_in,
                              void* d_out, int out_size, void* d_ws, size_t ws_size,
                              hipStream_t stream) {
  const float* x     = (const float*)d_in[0];
  const int*   adj   = (const int*)d_in[1];
  const float* W_fc  = (const float*)d_in[2];
  const float* b_fc  = (const float*)d_in[3];
  const float* W_qfc = (const float*)d_in[4];
  const float* b_qfc = (const float*)d_in[5];
  const float* W_fin = (const float*)d_in[6];
  const float* b_fin = (const float*)d_in[7];
  float* out = (float*)d_out;

  char* ws = (char*)d_ws;
  size_t off = 0;
  auto alloc = [&](size_t bytes) {
    char* p = ws + off;
    off += (bytes + 255) & ~(size_t)255;
    return p;
  };
  u16* xnew_bf = (u16*)alloc((size_t)N_TOK * DMODEL * 2);
  u16* q_bf    = (u16*)alloc((size_t)N_TOK * DMODEL * 2);
  u16* xT      = (u16*)alloc((size_t)DMODEL * N_TOK * 2);
  u16* out2_bf = (u16*)alloc((size_t)N_TOK * DMODEL * 2);
  u32* bits    = (u32*)alloc((size_t)N_TOK * NWORDS * 4);
  size_t base_off = off;
  float* Opart  = (float*)alloc((size_t)4 * N_TOK * DMODEL * 4);
  float* mlpart = (float*)alloc((size_t)4 * NHEAD * N_TOK * 2 * 4);
  size_t need4 = off;
  size_t need2 = base_off + ((size_t)2 * N_TOK * DMODEL * 4 + 256) +
                 ((size_t)2 * NHEAD * N_TOK * 2 * 4 + 256);
  const int split = (ws_size >= need4) ? 4 : (ws_size >= need2) ? 2 : 1;

  pack_adj<<<N_TOK * NWORDS / 256, 256, 0, stream>>>(adj, bits);
  dim3 ggrid(N_TOK / 128, DMODEL / 128);
  gemm_nt<0, 0><<<ggrid, 256, 0, stream>>>(x, W_fc, b_fc, nullptr, xnew_bf, nullptr);
  gemm_nt<1, 0><<<ggrid, 256, 0, stream>>>(xnew_bf, W_qfc, b_qfc, nullptr, q_bf, nullptr);
  transpose_bf<<<dim3(N_TOK / 64, DMODEL / 64), 256, 0, stream>>>(xnew_bf, xT);
  if (split == 4) {
    attn_fused<4><<<dim3(N_TOK / 64, NHEAD, 4), 256, 0, stream>>>(
        xnew_bf, q_bf, xT, bits, x, out2_bf, Opart, mlpart);
    attn_combine<4><<<N_TOK * DMODEL / 4 / 256, 256, 0, stream>>>(Opart, mlpart, x, out2_bf);
  } else if (split == 2) {
    attn_fused<2><<<dim3(N_TOK / 64, NHEAD, 2), 256, 0, stream>>>(
        xnew_bf, q_bf, xT, bits, x, out2_bf, Opart, mlpart);
    attn_combine<2><<<N_TOK * DMODEL / 4 / 256, 256, 0, stream>>>(Opart, mlpart, x, out2_bf);
  } else {
    attn_fused<1><<<dim3(N_TOK / 64, NHEAD, 1), 256, 0, stream>>>(
        xnew_bf, q_bf, xT, bits, x, out2_bf, Opart, mlpart);
  }
  gemm_nt<1, 1><<<ggrid, 256, 0, stream>>>(out2_bf, W_fin, b_fin, x, nullptr, out);
}